// Round 1
// baseline (1266.730 us; speedup 1.0000x reference)
//
#include <hip/hip_runtime.h>
#include <math.h>

// ---------------- kernels ----------------

__global__ void k_init(float* __restrict__ deg, float* __restrict__ cs,
                       float* __restrict__ csq, int n) {
    int i = blockIdx.x * blockDim.x + threadIdx.x;
    if (i < n) deg[i] = 1.0f;          // self-loop
    if (i < 256) { cs[i] = 0.f; csq[i] = 0.f; }
}

__global__ void k_degcount(const int* __restrict__ dst, float* __restrict__ deg, int E) {
    int e = blockIdx.x * blockDim.x + threadIdx.x;
    if (e < E) atomicAdd(&deg[dst[e]], 1.0f);
}

__global__ void k_dinv(const float* __restrict__ deg, float* __restrict__ dinv, int n) {
    int i = blockIdx.x * blockDim.x + threadIdx.x;
    if (i < n) dinv[i] = rsqrtf(deg[i]);
}

// h2 = rowscale(dinv) * ((X*scale+shift) @ W); agg initialized = h2 (self-loop term).
// scale/shift == nullptr for the first layer (raw X input).
__global__ __launch_bounds__(256) void k_gemm(
    const float* __restrict__ X, const float* __restrict__ W,
    const float* __restrict__ dinv,
    const float* __restrict__ scale, const float* __restrict__ shift,
    float* __restrict__ h2, float* __restrict__ agg,
    int N, int K, int M)
{
    __shared__ float xs[8][256];
    const int i0 = blockIdx.x * 8;
    const int t = threadIdx.x;
    const bool aff = (scale != nullptr);
    float sc = 1.f, sh = 0.f;
    if (aff && t < K) { sc = scale[t]; sh = shift[t]; }
    #pragma unroll
    for (int r = 0; r < 8; ++r) {
        int i = i0 + r;
        float v = 0.f;
        if (i < N && t < K) {
            v = X[(long)i * K + t];
            v = v * sc + sh;           // identity when !aff (sc=1, sh=0)
        }
        xs[r][t] = v;
    }
    __syncthreads();
    if (t < M) {
        float acc[8];
        #pragma unroll
        for (int r = 0; r < 8; ++r) acc[r] = 0.f;
        #pragma unroll 4
        for (int k = 0; k < K; ++k) {
            float w = W[(long)k * M + t];
            #pragma unroll
            for (int r = 0; r < 8; ++r) acc[r] += xs[r][k] * w;
        }
        #pragma unroll
        for (int r = 0; r < 8; ++r) {
            int i = i0 + r;
            if (i < N) {
                float v = acc[r] * dinv[i];
                h2[(long)i * M + t]  = v;
                agg[(long)i * M + t] = v;
            }
        }
    }
}

// agg[dst] += h2[src] for real edges; block = 4 edges x 64 feature lanes
__global__ __launch_bounds__(256) void k_scatter(
    const int* __restrict__ src, const int* __restrict__ dst,
    const float* __restrict__ h2, float* __restrict__ agg,
    int E, int M)
{
    int e = blockIdx.x * 4 + (threadIdx.x >> 6);
    int j = blockIdx.y * 64 + (threadIdx.x & 63);
    if (e < E && j < M) {
        int s = src[e];
        int d = dst[e];
        atomicAdd(&agg[(long)d * M + j], h2[(long)s * M + j]);
    }
}

// tmp = relu(agg*dinv + b); accumulate column sum/sumsq
__global__ __launch_bounds__(256) void k_post_stats(
    const float* __restrict__ agg, const float* __restrict__ dinv,
    const float* __restrict__ b, float* __restrict__ tmp,
    float* __restrict__ cs, float* __restrict__ csq,
    int N, int M)
{
    const int j = threadIdx.x;
    const int i0 = blockIdx.x * 64;
    if (j >= M) return;
    float s = 0.f, s2 = 0.f;
    const float bj = b[j];
    for (int r = 0; r < 64; ++r) {
        int i = i0 + r;
        if (i < N) {
            float v = agg[(long)i * M + j] * dinv[i] + bj;
            v = fmaxf(v, 0.f);
            tmp[(long)i * M + j] = v;
            s += v;
            s2 += v * v;
        }
    }
    atomicAdd(&cs[j], s);
    atomicAdd(&csq[j], s2);
}

// scale/shift for BN affine, consumed by next layer's GEMM X-load; re-zero stats
__global__ void k_bn_finalize(
    const float* __restrict__ g, const float* __restrict__ be,
    float* __restrict__ cs, float* __restrict__ csq,
    float* __restrict__ scale, float* __restrict__ shift,
    int M, float invN)
{
    int j = threadIdx.x;
    if (j < M) {
        float mu  = cs[j] * invN;
        float var = csq[j] * invN - mu * mu;
        float sc  = g[j] * rsqrtf(var + 1e-5f);
        scale[j] = sc;
        shift[j] = be[j] - mu * sc;
    }
    if (j < 256) { cs[j] = 0.f; csq[j] = 0.f; }   // ready for next layer
}

// final layer: v = agg*dinv + b; out = log_softmax(v) over 17 classes
__global__ void k_final(const float* __restrict__ agg, const float* __restrict__ dinv,
                        const float* __restrict__ b, float* __restrict__ out, int N)
{
    int i = blockIdx.x * blockDim.x + threadIdx.x;
    if (i >= N) return;
    const int M = 17;
    float v[17];
    float di = dinv[i];
    float m = -INFINITY;
    #pragma unroll
    for (int j = 0; j < M; ++j) {
        v[j] = agg[(long)i * M + j] * di + b[j];
        m = fmaxf(m, v[j]);
    }
    float s = 0.f;
    #pragma unroll
    for (int j = 0; j < M; ++j) s += expf(v[j] - m);
    float l = logf(s) + m;
    #pragma unroll
    for (int j = 0; j < M; ++j) out[(long)i * M + j] = v[j] - l;
}

// ---------------- launch ----------------

extern "C" void kernel_launch(void* const* d_in, const int* in_sizes, int n_in,
                              void* d_out, int out_size, void* d_ws, size_t ws_size,
                              hipStream_t stream)
{
    const int dims[6] = {256, 220, 150, 100, 60, 17};
    const int N = in_sizes[0] / dims[0];      // 10000
    const int E = in_sizes[1] / 2;            // 320000

    const float* x  = (const float*)d_in[0];
    const int* ei   = (const int*)d_in[1];
    const int* srcv = ei;
    const int* dstv = ei + E;
    const float* Wl[5], *bl[5];
    for (int l = 0; l < 5; ++l) {
        Wl[l] = (const float*)d_in[2 + 2 * l];
        bl[l] = (const float*)d_in[3 + 2 * l];
    }
    const float* gl[4], *bel[4];
    for (int l = 0; l < 4; ++l) {
        gl[l]  = (const float*)d_in[12 + 2 * l];
        bel[l] = (const float*)d_in[13 + 2 * l];
    }
    float* out = (float*)d_out;

    // workspace layout (floats)
    float* ws = (float*)d_ws;
    const long OFF_DEG  = 0;            // N
    const long OFF_DINV = 16384;        // N
    const long OFF_CS   = 32768;        // 256
    const long OFF_CSQ  = 33024;        // 256
    const long OFF_SC   = 33280;        // 256
    const long OFF_SH   = 33536;        // 256
    const long BUF      = (long)N * 224 + 1024;
    const long OFF_H2   = 40960;
    const long OFF_AGG  = OFF_H2 + BUF;
    const long OFF_TMP  = OFF_AGG + BUF;

    float* deg  = ws + OFF_DEG;
    float* dinv = ws + OFF_DINV;
    float* cs   = ws + OFF_CS;
    float* csq  = ws + OFF_CSQ;
    float* scl  = ws + OFF_SC;
    float* shf  = ws + OFF_SH;
    float* h2   = ws + OFF_H2;
    float* agg  = ws + OFF_AGG;
    float* tmp  = ws + OFF_TMP;

    const int nBlk = (N + 255) / 256;

    k_init<<<nBlk, 256, 0, stream>>>(deg, cs, csq, N);
    k_degcount<<<(E + 255) / 256, 256, 0, stream>>>(dstv, deg, E);
    k_dinv<<<nBlk, 256, 0, stream>>>(deg, dinv, N);

    const float invN = 1.0f / (float)N;

    for (int l = 0; l < 5; ++l) {
        const int K = dims[l];
        const int M = dims[l + 1];
        const float* X = (l == 0) ? x : tmp;
        const float* sc_p = (l == 0) ? nullptr : scl;
        const float* sh_p = (l == 0) ? nullptr : shf;

        k_gemm<<<(N + 7) / 8, 256, 0, stream>>>(X, Wl[l], dinv, sc_p, sh_p,
                                                h2, agg, N, K, M);

        dim3 sg((E + 3) / 4, (M + 63) / 64);
        k_scatter<<<sg, 256, 0, stream>>>(srcv, dstv, h2, agg, E, M);

        if (l < 4) {
            k_post_stats<<<(N + 63) / 64, 256, 0, stream>>>(agg, dinv, bl[l], tmp,
                                                            cs, csq, N, M);
            k_bn_finalize<<<1, 256, 0, stream>>>(gl[l], bel[l], cs, csq, scl, shf,
                                                 M, invN);
        } else {
            k_final<<<nBlk, 256, 0, stream>>>(agg, dinv, bl[l], out, N);
        }
    }
}

// Round 2
// 594.747 us; speedup vs baseline: 2.1299x; 2.1299x over previous
//
#include <hip/hip_runtime.h>
#include <math.h>

// ---------------- CSR construction ----------------

__global__ void k_zero(int* __restrict__ cnt, float* __restrict__ cs,
                       float* __restrict__ csq, int n) {
    int i = blockIdx.x * blockDim.x + threadIdx.x;
    if (i < n) cnt[i] = 0;
    if (i < 256) { cs[i] = 0.f; csq[i] = 0.f; }
}

__global__ void k_hist(const int* __restrict__ dst, int* __restrict__ cnt, int E) {
    int e = blockIdx.x * blockDim.x + threadIdx.x;
    if (e < E) atomicAdd(&cnt[dst[e]], 1);
}

// single-block scan over N counts -> row_start (exclusive), cursor copy, dinv
__global__ __launch_bounds__(1024) void k_scan(
    const int* __restrict__ cnt, int* __restrict__ row_start,
    int* __restrict__ cursor, float* __restrict__ dinv, int N)
{
    __shared__ int sh[1024];
    const int tid = threadIdx.x;
    const int chunk = (N + 1023) >> 10;     // ≤16 for N ≤ 16384
    int loc[16];
    const int base = tid * chunk;
    int sum = 0;
    for (int c = 0; c < chunk; ++c) {
        int i = base + c;
        int v = (i < N) ? cnt[i] : 0;
        loc[c] = sum;
        sum += v;
    }
    sh[tid] = sum;
    __syncthreads();
    for (int off = 1; off < 1024; off <<= 1) {
        int v = (tid >= off) ? sh[tid - off] : 0;
        __syncthreads();
        sh[tid] += v;
        __syncthreads();
    }
    const int excl = sh[tid] - sum;
    for (int c = 0; c < chunk; ++c) {
        int i = base + c;
        if (i < N) {
            int rs = excl + loc[c];
            row_start[i] = rs;
            cursor[i] = rs;
            dinv[i] = rsqrtf(1.0f + (float)cnt[i]);   // deg incl. self-loop
        }
    }
    if (tid == 1023) row_start[N] = sh[1023];
}

__global__ void k_fill(const int* __restrict__ src, const int* __restrict__ dst,
                       int* __restrict__ cursor, int* __restrict__ csr_src, int E) {
    int e = blockIdx.x * blockDim.x + threadIdx.x;
    if (e < E) {
        int pos = atomicAdd(&cursor[dst[e]], 1);
        csr_src[pos] = src[e];
    }
}

// ---------------- compute kernels ----------------

// h2 = rowscale(dinv) * ((X*scale+shift) @ W).  scale==nullptr on layer 0.
__global__ __launch_bounds__(256) void k_gemm(
    const float* __restrict__ X, const float* __restrict__ W,
    const float* __restrict__ dinv,
    const float* __restrict__ scale, const float* __restrict__ shift,
    float* __restrict__ h2, int N, int K, int M)
{
    __shared__ float xs[16][256];
    const int i0 = blockIdx.x * 16;
    const int t = threadIdx.x;
    float sc = 1.f, sh = 0.f;
    if (scale != nullptr && t < K) { sc = scale[t]; sh = shift[t]; }
    #pragma unroll
    for (int r = 0; r < 16; ++r) {
        int i = i0 + r;
        float v = 0.f;
        if (i < N && t < K) v = X[(long)i * K + t] * sc + sh;
        xs[r][t] = v;
    }
    __syncthreads();
    if (t < M) {
        float acc[16];
        #pragma unroll
        for (int r = 0; r < 16; ++r) acc[r] = 0.f;
        #pragma unroll 8
        for (int k = 0; k < K; ++k) {
            float w = W[(long)k * M + t];
            #pragma unroll
            for (int r = 0; r < 16; ++r) acc[r] += xs[r][k] * w;
        }
        #pragma unroll
        for (int r = 0; r < 16; ++r) {
            int i = i0 + r;
            if (i < N) h2[(long)i * M + t] = acc[r] * dinv[i];
        }
    }
}

// tmp[i][j] = (h2[i][j] + sum_{e in CSR[i]} h2[src_e][j]) * dinv[i] + b[j]  (+relu)
__global__ __launch_bounds__(256) void k_agg(
    const int* __restrict__ row_start, const int* __restrict__ csr_src,
    const float* __restrict__ h2, const float* __restrict__ dinv,
    const float* __restrict__ b, float* __restrict__ tmp,
    int N, int M, int do_relu)
{
    const int j = threadIdx.x;
    const int i = blockIdx.x * blockDim.y + threadIdx.y;
    if (i >= N || j >= M) return;
    const int s0 = row_start[i];
    const int s1 = row_start[i + 1];
    float acc = h2[(long)i * M + j];          // self-loop term
    int e = s0;
    for (; e + 3 < s1; e += 4) {
        int a = csr_src[e], bb = csr_src[e + 1], c = csr_src[e + 2], d = csr_src[e + 3];
        float va = h2[(long)a * M + j];
        float vb = h2[(long)bb * M + j];
        float vc = h2[(long)c * M + j];
        float vd = h2[(long)d * M + j];
        acc += va; acc += vb; acc += vc; acc += vd;
    }
    for (; e < s1; ++e) acc += h2[(long)csr_src[e] * M + j];
    acc = acc * dinv[i] + b[j];
    if (do_relu) acc = fmaxf(acc, 0.f);
    tmp[(long)i * M + j] = acc;
}

__global__ __launch_bounds__(256) void k_stats(
    const float* __restrict__ tmp, float* __restrict__ cs, float* __restrict__ csq,
    int N, int M)
{
    const int j = threadIdx.x;
    if (j >= M) return;
    const int i0 = blockIdx.x * 64;
    float s = 0.f, s2 = 0.f;
    for (int r = 0; r < 64; ++r) {
        int i = i0 + r;
        if (i < N) {
            float v = tmp[(long)i * M + j];
            s += v; s2 += v * v;
        }
    }
    atomicAdd(&cs[j], s);
    atomicAdd(&csq[j], s2);
}

__global__ void k_bn_finalize(
    const float* __restrict__ g, const float* __restrict__ be,
    float* __restrict__ cs, float* __restrict__ csq,
    float* __restrict__ scale, float* __restrict__ shift,
    int M, float invN)
{
    int j = threadIdx.x;
    if (j < M) {
        float mu  = cs[j] * invN;
        float var = csq[j] * invN - mu * mu;
        float sc  = g[j] * rsqrtf(var + 1e-5f);
        scale[j] = sc;
        shift[j] = be[j] - mu * sc;
    }
    if (j < 256) { cs[j] = 0.f; csq[j] = 0.f; }
}

// tmp already = logits (bias included); log_softmax over 17 classes
__global__ void k_final(const float* __restrict__ tmp, float* __restrict__ out, int N) {
    int i = blockIdx.x * blockDim.x + threadIdx.x;
    if (i >= N) return;
    const int M = 17;
    float v[17];
    float m = -INFINITY;
    #pragma unroll
    for (int j = 0; j < M; ++j) { v[j] = tmp[(long)i * M + j]; m = fmaxf(m, v[j]); }
    float s = 0.f;
    #pragma unroll
    for (int j = 0; j < M; ++j) s += expf(v[j] - m);
    float l = logf(s) + m;
    #pragma unroll
    for (int j = 0; j < M; ++j) out[(long)i * M + j] = v[j] - l;
}

// ---------------- launch ----------------

extern "C" void kernel_launch(void* const* d_in, const int* in_sizes, int n_in,
                              void* d_out, int out_size, void* d_ws, size_t ws_size,
                              hipStream_t stream)
{
    const int dims[6] = {256, 220, 150, 100, 60, 17};
    const int N = in_sizes[0] / dims[0];      // 10000
    const int E = in_sizes[1] / 2;            // 320000

    const float* x  = (const float*)d_in[0];
    const int* ei   = (const int*)d_in[1];
    const int* srcv = ei;
    const int* dstv = ei + E;
    const float* Wl[5], *bl[5];
    for (int l = 0; l < 5; ++l) {
        Wl[l] = (const float*)d_in[2 + 2 * l];
        bl[l] = (const float*)d_in[3 + 2 * l];
    }
    const float* gl[4], *bel[4];
    for (int l = 0; l < 4; ++l) {
        gl[l]  = (const float*)d_in[12 + 2 * l];
        bel[l] = (const float*)d_in[13 + 2 * l];
    }
    float* out = (float*)d_out;

    // ---- workspace layout (bytes, 256-aligned) ----
    char* w = (char*)d_ws;
    const long NB   = ((long)N * 4 + 255) & ~255L;          // per-N int/float array
    const long NB1  = ((long)(N + 1) * 4 + 255) & ~255L;
    const long EB   = ((long)E * 4 + 255) & ~255L;
    const long FB   = ((long)N * 224 * 4 + 255) & ~255L;    // feature buffer (max M=220)

    float* dinv     = (float*)(w);                 long o = NB;
    float* cs       = (float*)(w + o);             o += 1024;
    float* csq      = (float*)(w + o);             o += 1024;
    float* scl      = (float*)(w + o);             o += 1024;
    float* shf      = (float*)(w + o);             o += 1024;
    int*   cnt      = (int*)(w + o);               o += NB;
    int*   row_start= (int*)(w + o);               o += NB1;
    int*   cursor   = (int*)(w + o);               o += NB;
    int*   csr_src  = (int*)(w + o);               o += EB;
    float* h2       = (float*)(w + o);             o += FB;
    float* tmp      = (float*)(w + o);             o += FB;

    const int nBlk = (N + 255) / 256;
    const int eBlk = (E + 255) / 256;

    k_zero<<<nBlk, 256, 0, stream>>>(cnt, cs, csq, N);
    k_hist<<<eBlk, 256, 0, stream>>>(dstv, cnt, E);
    k_scan<<<1, 1024, 0, stream>>>(cnt, row_start, cursor, dinv, N);
    k_fill<<<eBlk, 256, 0, stream>>>(srcv, dstv, cursor, csr_src, E);

    const float invN = 1.0f / (float)N;

    for (int l = 0; l < 5; ++l) {
        const int K = dims[l];
        const int M = dims[l + 1];
        const float* X = (l == 0) ? x : tmp;
        const float* sc_p = (l == 0) ? nullptr : scl;
        const float* sh_p = (l == 0) ? nullptr : shf;

        k_gemm<<<(N + 15) / 16, 256, 0, stream>>>(X, Wl[l], dinv, sc_p, sh_p,
                                                  h2, N, K, M);

        // lanes = ceil(M/64)*64, nodes/block = max(1, 256/lanes)
        int lanes = ((M + 63) / 64) * 64;
        int ynodes = lanes <= 64 ? 4 : (lanes <= 128 ? 2 : 1);
        dim3 ablk(lanes, ynodes);
        int agrid = (N + ynodes - 1) / ynodes;
        k_agg<<<agrid, ablk, 0, stream>>>(row_start, csr_src, h2, dinv, bl[l],
                                          tmp, N, M, (l < 4) ? 1 : 0);

        if (l < 4) {
            k_stats<<<(N + 63) / 64, 256, 0, stream>>>(tmp, cs, csq, N, M);
            k_bn_finalize<<<1, 256, 0, stream>>>(gl[l], bel[l], cs, csq, scl, shf,
                                                 M, invN);
        } else {
            k_final<<<nBlk, 256, 0, stream>>>(tmp, out, N);
        }
    }
}

// Round 3
// 488.998 us; speedup vs baseline: 2.5905x; 1.2163x over previous
//
#include <hip/hip_runtime.h>
#include <math.h>

typedef unsigned short ushort_t;
typedef unsigned int uint_t;

__device__ __forceinline__ float bf2f(ushort_t u) {
    union { uint_t i; float f; } x; x.i = ((uint_t)u) << 16; return x.f;
}
__device__ __forceinline__ ushort_t f2bf(float f) {
    union { float f; uint_t i; } x; x.f = f;
    uint_t r = x.i + 0x7FFFu + ((x.i >> 16) & 1u);
    return (ushort_t)(r >> 16);
}

// ---------------- CSR construction ----------------

__global__ void k_zero(int* __restrict__ cnt, float* __restrict__ cs,
                       float* __restrict__ csq, int n) {
    int i = blockIdx.x * blockDim.x + threadIdx.x;
    if (i < n) cnt[i] = 0;
    if (i < 256) { cs[i] = 0.f; csq[i] = 0.f; }
}

__global__ void k_hist(const int* __restrict__ dst, int* __restrict__ cnt, int E) {
    int e = blockIdx.x * blockDim.x + threadIdx.x;
    if (e < E) atomicAdd(&cnt[dst[e]], 1);
}

__global__ __launch_bounds__(1024) void k_scan(
    const int* __restrict__ cnt, int* __restrict__ row_start,
    int* __restrict__ cursor, float* __restrict__ dinv, int N)
{
    __shared__ int sh[1024];
    const int tid = threadIdx.x;
    const int chunk = (N + 1023) >> 10;
    int loc[16];
    const int base = tid * chunk;
    int sum = 0;
    for (int c = 0; c < chunk; ++c) {
        int i = base + c;
        int v = (i < N) ? cnt[i] : 0;
        loc[c] = sum;
        sum += v;
    }
    sh[tid] = sum;
    __syncthreads();
    for (int off = 1; off < 1024; off <<= 1) {
        int v = (tid >= off) ? sh[tid - off] : 0;
        __syncthreads();
        sh[tid] += v;
        __syncthreads();
    }
    const int excl = sh[tid] - sum;
    for (int c = 0; c < chunk; ++c) {
        int i = base + c;
        if (i < N) {
            int rs = excl + loc[c];
            row_start[i] = rs;
            cursor[i] = rs;
            dinv[i] = rsqrtf(1.0f + (float)cnt[i]);
        }
    }
    if (tid == 1023) row_start[N] = sh[1023];
}

__global__ void k_fill(const int* __restrict__ src, const int* __restrict__ dst,
                       int* __restrict__ cursor, int* __restrict__ csr_src, int E) {
    int e = blockIdx.x * blockDim.x + threadIdx.x;
    if (e < E) {
        int pos = atomicAdd(&cursor[dst[e]], 1);
        csr_src[pos] = src[e];
    }
}

// ---------------- prep kernels ----------------

__global__ void k_cvtx(const float* __restrict__ x, ushort_t* __restrict__ xb, int n) {
    int i = blockIdx.x * 256 + threadIdx.x;
    if (i < n) xb[i] = f2bf(x[i]);
}

// Wt[j][k] = bf16(scale[k] * W[k][j]), zero-padded to Mp x Kp
__global__ void k_prepW(const float* __restrict__ W, const float* __restrict__ scale,
                        ushort_t* __restrict__ Wt, int K, int M, int Kp)
{
    int k = blockIdx.x * 64 + threadIdx.x;
    int j = blockIdx.y;
    if (k >= Kp) return;
    float v = 0.f;
    if (k < K && j < M) {
        float s = (scale != nullptr) ? scale[k] : 1.f;
        v = s * W[(long)k * M + j];
    }
    Wt[(long)j * Kp + k] = f2bf(v);
}

// wbias[j] = sum_k shift[k]*W[k][j]  (0 if shift==nullptr or j>=M)
__global__ void k_prepb(const float* __restrict__ W, const float* __restrict__ shift,
                        float* __restrict__ wbias, int K, int M, int Mp)
{
    int j = threadIdx.x;
    if (j >= Mp && j >= 256) return;
    if (j < Mp) {
        float s = 0.f;
        if (shift != nullptr && j < M)
            for (int k = 0; k < K; ++k) s += shift[k] * W[(long)k * M + j];
        wbias[j] = s;
    }
}

// ---------------- MFMA GEMM ----------------
// h2[i][j] = bf16( (Xb[i,:]·Wt[j,:] + wbias[j]) * dinv[i] ),  i<N, j<Mp (pad cols = 0)
template<int KP>
__global__ __launch_bounds__(64) void k_gemm_mfma(
    const ushort_t* __restrict__ Xb, const ushort_t* __restrict__ Wt,
    const float* __restrict__ wbias, const float* __restrict__ dinv,
    ushort_t* __restrict__ h2, int N, int Mp)
{
    typedef __attribute__((ext_vector_type(8))) short short8;
    typedef __attribute__((ext_vector_type(4))) float floatx4;
    const int lane = threadIdx.x;
    const int m = lane & 15;
    const int quad = lane >> 4;
    const int i0 = blockIdx.x * 16;
    const int j0 = blockIdx.y * 64;
    const int ntiles = min(4, (Mp - j0) >> 4);

    floatx4 acc[4];
    #pragma unroll
    for (int t = 0; t < 4; ++t) { acc[t].x = 0.f; acc[t].y = 0.f; acc[t].z = 0.f; acc[t].w = 0.f; }

    const int ra = min(i0 + m, N - 1);
    const ushort_t* arow = Xb + (long)ra * KP + quad * 8;
    const ushort_t* brow = Wt + (long)(j0 + m) * KP + quad * 8;

    #pragma unroll
    for (int k0 = 0; k0 < KP; k0 += 32) {
        short8 av = *(const short8*)(arow + k0);
        #pragma unroll
        for (int t = 0; t < 4; ++t) {
            if (t < ntiles) {
                short8 bv = *(const short8*)(brow + (long)t * 16 * KP + k0);
                acc[t] = __builtin_amdgcn_mfma_f32_16x16x32_bf16(av, bv, acc[t], 0, 0, 0);
            }
        }
    }

    #pragma unroll
    for (int t = 0; t < 4; ++t) {
        if (t < ntiles) {
            int j = j0 + t * 16 + m;
            float wb = wbias[j];
            #pragma unroll
            for (int r = 0; r < 4; ++r) {
                int i = i0 + quad * 4 + r;
                if (i < N) h2[(long)i * Mp + j] = f2bf((acc[t][r] + wb) * dinv[i]);
            }
        }
    }
}

// ---------------- aggregation (CSR gather, bf16 pairs) ----------------
// mode 0: tmpb[i][j] = bf16(relu(acc*dinv+b)), pad cols [M,2*halfK) zeroed
// mode 1: tmpf[i][j] = acc*dinv+b (fp32, j<M only)
__global__ __launch_bounds__(256) void k_agg(
    const int* __restrict__ row_start, const int* __restrict__ csr_src,
    const ushort_t* __restrict__ h2, int hstride,
    const float* __restrict__ dinv, const float* __restrict__ b,
    ushort_t* __restrict__ tmpb, int tstride, float* __restrict__ tmpf,
    int N, int M, int halfK, int mode)
{
    const int jp = threadIdx.x;
    const int i = blockIdx.x * 2 + threadIdx.y;
    if (i >= N || jp >= halfK) return;
    const int j0 = jp * 2;
    if (j0 >= M) {
        if (mode == 0) ((uint_t*)(tmpb + (long)i * tstride))[jp] = 0u;
        return;
    }
    const int s0 = row_start[i];
    const int s1 = row_start[i + 1];
    const ushort_t* hrow = h2 + (long)i * hstride;
    uint_t v = *(const uint_t*)(hrow + j0);
    float a0 = bf2f((ushort_t)(v & 0xffff));
    float a1 = bf2f((ushort_t)(v >> 16));
    int e = s0;
    for (; e + 3 < s1; e += 4) {
        int n0 = csr_src[e], n1 = csr_src[e + 1], n2 = csr_src[e + 2], n3 = csr_src[e + 3];
        uint_t w0 = *(const uint_t*)(h2 + (long)n0 * hstride + j0);
        uint_t w1 = *(const uint_t*)(h2 + (long)n1 * hstride + j0);
        uint_t w2 = *(const uint_t*)(h2 + (long)n2 * hstride + j0);
        uint_t w3 = *(const uint_t*)(h2 + (long)n3 * hstride + j0);
        a0 += bf2f((ushort_t)(w0 & 0xffff)); a1 += bf2f((ushort_t)(w0 >> 16));
        a0 += bf2f((ushort_t)(w1 & 0xffff)); a1 += bf2f((ushort_t)(w1 >> 16));
        a0 += bf2f((ushort_t)(w2 & 0xffff)); a1 += bf2f((ushort_t)(w2 >> 16));
        a0 += bf2f((ushort_t)(w3 & 0xffff)); a1 += bf2f((ushort_t)(w3 >> 16));
    }
    for (; e < s1; ++e) {
        uint_t w = *(const uint_t*)(h2 + (long)csr_src[e] * hstride + j0);
        a0 += bf2f((ushort_t)(w & 0xffff));
        a1 += bf2f((ushort_t)(w >> 16));
    }
    const float di = dinv[i];
    const int j1 = j0 + 1;
    float r0 = a0 * di + b[j0];
    float r1 = (j1 < M) ? (a1 * di + b[j1]) : 0.f;
    if (mode == 0) {
        r0 = fmaxf(r0, 0.f);
        r1 = fmaxf(r1, 0.f);
        uint_t pk = (uint_t)f2bf(r0) | ((uint_t)f2bf(r1) << 16);
        ((uint_t*)(tmpb + (long)i * tstride))[jp] = pk;
    } else {
        float* orow = tmpf + (long)i * 32;
        orow[j0] = r0;
        if (j1 < M) orow[j1] = r1;
    }
}

// ---------------- BN stats / finalize ----------------

__global__ __launch_bounds__(256) void k_stats(
    const ushort_t* __restrict__ tmpb, int tstride,
    float* __restrict__ cs, float* __restrict__ csq, int N, int M)
{
    const int j = threadIdx.x;
    if (j >= M) return;
    const int i0 = blockIdx.x * 64;
    float s = 0.f, s2 = 0.f;
    for (int r = 0; r < 64; ++r) {
        int i = i0 + r;
        if (i < N) {
            float v = bf2f(tmpb[(long)i * tstride + j]);
            s += v; s2 += v * v;
        }
    }
    atomicAdd(&cs[j], s);
    atomicAdd(&csq[j], s2);
}

__global__ void k_bn_finalize(
    const float* __restrict__ g, const float* __restrict__ be,
    float* __restrict__ cs, float* __restrict__ csq,
    float* __restrict__ scale, float* __restrict__ shift,
    int M, float invN)
{
    int j = threadIdx.x;
    if (j < M) {
        float mu  = cs[j] * invN;
        float var = csq[j] * invN - mu * mu;
        float sc  = g[j] * rsqrtf(var + 1e-5f);
        scale[j] = sc;
        shift[j] = be[j] - mu * sc;
    }
    if (j < 256) { cs[j] = 0.f; csq[j] = 0.f; }
}

// ---------------- final log_softmax ----------------

__global__ void k_final(const float* __restrict__ tmpf, float* __restrict__ out, int N) {
    int i = blockIdx.x * blockDim.x + threadIdx.x;
    if (i >= N) return;
    const int M = 17;
    float v[17];
    float m = -INFINITY;
    #pragma unroll
    for (int j = 0; j < M; ++j) { v[j] = tmpf[(long)i * 32 + j]; m = fmaxf(m, v[j]); }
    float s = 0.f;
    #pragma unroll
    for (int j = 0; j < M; ++j) s += expf(v[j] - m);
    float l = logf(s) + m;
    #pragma unroll
    for (int j = 0; j < M; ++j) out[(long)i * M + j] = v[j] - l;
}

// ---------------- launch ----------------

static inline int pad16(int v) { return (v + 15) & ~15; }
static inline int pad32(int v) { return (v + 31) & ~31; }

extern "C" void kernel_launch(void* const* d_in, const int* in_sizes, int n_in,
                              void* d_out, int out_size, void* d_ws, size_t ws_size,
                              hipStream_t stream)
{
    const int dims[6] = {256, 220, 150, 100, 60, 17};
    const int N = in_sizes[0] / dims[0];      // 10000
    const int E = in_sizes[1] / 2;            // 320000

    const float* x  = (const float*)d_in[0];
    const int* ei   = (const int*)d_in[1];
    const int* srcv = ei;
    const int* dstv = ei + E;
    const float* Wl[5], *bl[5];
    for (int l = 0; l < 5; ++l) {
        Wl[l] = (const float*)d_in[2 + 2 * l];
        bl[l] = (const float*)d_in[3 + 2 * l];
    }
    const float* gl[4], *bel[4];
    for (int l = 0; l < 4; ++l) {
        gl[l]  = (const float*)d_in[12 + 2 * l];
        bel[l] = (const float*)d_in[13 + 2 * l];
    }
    float* out = (float*)d_out;

    // ---- workspace layout (bytes, 256-aligned) ----
    char* w = (char*)d_ws;
    const long NB   = ((long)N * 4 + 255) & ~255L;
    const long NB1  = ((long)(N + 1) * 4 + 255) & ~255L;
    const long EB   = ((long)E * 4 + 255) & ~255L;
    const long XBB  = ((long)N * 256 * 2 + 255) & ~255L;   // bf16 x
    const long FBB  = ((long)N * 224 * 2 + 255) & ~255L;   // bf16 feature buf
    const long WTB  = ((long)224 * 256 * 2 + 255) & ~255L; // bf16 Wt (max)
    const long TFB  = ((long)N * 32 * 4 + 255) & ~255L;    // fp32 final logits

    long o = 0;
    float* dinv      = (float*)(w + o);  o += NB;
    float* cs        = (float*)(w + o);  o += 1024;
    float* csq       = (float*)(w + o);  o += 1024;
    float* scl       = (float*)(w + o);  o += 1024;
    float* shf       = (float*)(w + o);  o += 1024;
    float* wbias     = (float*)(w + o);  o += 1024;
    int*   cnt       = (int*)(w + o);    o += NB;
    int*   row_start = (int*)(w + o);    o += NB1;
    int*   cursor    = (int*)(w + o);    o += NB;
    int*   csr_src   = (int*)(w + o);    o += EB;
    ushort_t* xb     = (ushort_t*)(w + o); o += XBB;
    ushort_t* Wt     = (ushort_t*)(w + o); o += WTB;
    ushort_t* h2     = (ushort_t*)(w + o); o += FBB;
    ushort_t* tmpb   = (ushort_t*)(w + o); o += FBB;
    float* tmpf      = (float*)(w + o);    o += TFB;

    const int nBlk = (N + 255) / 256;
    const int eBlk = (E + 255) / 256;

    k_zero<<<nBlk, 256, 0, stream>>>(cnt, cs, csq, N);
    k_hist<<<eBlk, 256, 0, stream>>>(dstv, cnt, E);
    k_scan<<<1, 1024, 0, stream>>>(cnt, row_start, cursor, dinv, N);
    k_fill<<<eBlk, 256, 0, stream>>>(srcv, dstv, cursor, csr_src, E);
    k_cvtx<<<(N * 256 + 255) / 256, 256, 0, stream>>>(x, xb, N * 256);

    const float invN = 1.0f / (float)N;

    for (int l = 0; l < 5; ++l) {
        const int K  = dims[l];
        const int M  = dims[l + 1];
        const int Kp = pad32(K);                 // input stride (multiple of 32)
        const int Mp = pad16(M);                 // h2 stride
        const int KpN = (l < 4) ? pad32(M) : 32; // tmp stride for next layer / final
        const ushort_t* X = (l == 0) ? xb : tmpb;
        const float* sc_p = (l == 0) ? nullptr : scl;
        const float* sh_p = (l == 0) ? nullptr : shf;

        k_prepW<<<dim3((Kp + 63) / 64, Mp), 64, 0, stream>>>(Wl[l], sc_p, Wt, K, M, Kp);
        k_prepb<<<1, 256, 0, stream>>>(Wl[l], sh_p, wbias, K, M, Mp);

        dim3 gg((N + 15) / 16, (Mp + 63) / 64);
        switch (Kp) {
            case 256: k_gemm_mfma<256><<<gg, 64, 0, stream>>>(X, Wt, wbias, dinv, h2, N, Mp); break;
            case 224: k_gemm_mfma<224><<<gg, 64, 0, stream>>>(X, Wt, wbias, dinv, h2, N, Mp); break;
            case 160: k_gemm_mfma<160><<<gg, 64, 0, stream>>>(X, Wt, wbias, dinv, h2, N, Mp); break;
            case 128: k_gemm_mfma<128><<<gg, 64, 0, stream>>>(X, Wt, wbias, dinv, h2, N, Mp); break;
            case  64: k_gemm_mfma< 64><<<gg, 64, 0, stream>>>(X, Wt, wbias, dinv, h2, N, Mp); break;
        }

        const int halfK = KpN / 2;
        dim3 ablk(128, 2);
        k_agg<<<(N + 1) / 2, ablk, 0, stream>>>(row_start, csr_src, h2, Mp, dinv, bl[l],
                                                tmpb, KpN, tmpf, N, M, halfK,
                                                (l < 4) ? 0 : 1);

        if (l < 4) {
            k_stats<<<(N + 63) / 64, 256, 0, stream>>>(tmpb, KpN, cs, csq, N, M);
            k_bn_finalize<<<1, 256, 0, stream>>>(gl[l], bel[l], cs, csq, scl, shf, M, invN);
        } else {
            k_final<<<nBlk, 256, 0, stream>>>(tmpf, out, N);
        }
    }
}

// Round 4
// 432.513 us; speedup vs baseline: 2.9288x; 1.1306x over previous
//
#include <hip/hip_runtime.h>
#include <math.h>

typedef unsigned short ushort_t;
typedef unsigned int uint_t;

__device__ __forceinline__ float bf2f(ushort_t u) {
    union { uint_t i; float f; } x; x.i = ((uint_t)u) << 16; return x.f;
}
__device__ __forceinline__ ushort_t f2bf(float f) {
    union { float f; uint_t i; } x; x.f = f;
    uint_t r = x.i + 0x7FFFu + ((x.i >> 16) & 1u);
    return (ushort_t)(r >> 16);
}

// ---------------- CSR construction ----------------

__global__ void k_zero(int* __restrict__ cnt, float* __restrict__ cs,
                       float* __restrict__ csq, int n) {
    int i = blockIdx.x * blockDim.x + threadIdx.x;
    if (i < n) cnt[i] = 0;
    if (i < 256) { cs[i] = 0.f; csq[i] = 0.f; }
}

__global__ void k_hist(const int* __restrict__ dst, int* __restrict__ cnt, int E) {
    int e = blockIdx.x * blockDim.x + threadIdx.x;
    if (e < E) atomicAdd(&cnt[dst[e]], 1);
}

__global__ __launch_bounds__(1024) void k_scan(
    const int* __restrict__ cnt, int* __restrict__ row_start,
    int* __restrict__ cursor, float* __restrict__ dinv, int N)
{
    __shared__ int sh[1024];
    const int tid = threadIdx.x;
    const int chunk = (N + 1023) >> 10;
    int loc[16];
    const int base = tid * chunk;
    int sum = 0;
    for (int c = 0; c < chunk; ++c) {
        int i = base + c;
        int v = (i < N) ? cnt[i] : 0;
        loc[c] = sum;
        sum += v;
    }
    sh[tid] = sum;
    __syncthreads();
    for (int off = 1; off < 1024; off <<= 1) {
        int v = (tid >= off) ? sh[tid - off] : 0;
        __syncthreads();
        sh[tid] += v;
        __syncthreads();
    }
    const int excl = sh[tid] - sum;
    for (int c = 0; c < chunk; ++c) {
        int i = base + c;
        if (i < N) {
            int rs = excl + loc[c];
            row_start[i] = rs;
            cursor[i] = rs;
            dinv[i] = rsqrtf(1.0f + (float)cnt[i]);
        }
    }
    if (tid == 1023) row_start[N] = sh[1023];
}

__global__ void k_fill(const int* __restrict__ src, const int* __restrict__ dst,
                       int* __restrict__ cursor, int* __restrict__ csr_src, int E) {
    int e = blockIdx.x * blockDim.x + threadIdx.x;
    if (e < E) {
        int pos = atomicAdd(&cursor[dst[e]], 1);
        csr_src[pos] = src[e];
    }
}

// ---------------- prep kernels ----------------

__global__ void k_cvtx(const float* __restrict__ x, ushort_t* __restrict__ xb, int n) {
    int i = blockIdx.x * 256 + threadIdx.x;
    if (i < n) xb[i] = f2bf(x[i]);
}

// Wt[j][k] = bf16(scale[k] * W[k][j]), zero-padded to Mp x Kp
__global__ void k_prepW(const float* __restrict__ W, const float* __restrict__ scale,
                        ushort_t* __restrict__ Wt, int K, int M, int Kp)
{
    int k = blockIdx.x * 64 + threadIdx.x;
    int j = blockIdx.y;
    if (k >= Kp) return;
    float v = 0.f;
    if (k < K && j < M) {
        float s = (scale != nullptr) ? scale[k] : 1.f;
        v = s * W[(long)k * M + j];
    }
    Wt[(long)j * Kp + k] = f2bf(v);
}

// wbias[j] = sum_k shift[k]*W[k][j]; parallel: 64 j-lanes x 4 k-groups per block
__global__ __launch_bounds__(256) void k_prepb(
    const float* __restrict__ W, const float* __restrict__ shift,
    float* __restrict__ wbias, int K, int M, int Mp)
{
    __shared__ float red[4][64];
    const int jl = threadIdx.x & 63;
    const int kg = threadIdx.x >> 6;
    const int j = blockIdx.x * 64 + jl;
    float s = 0.f;
    if (shift != nullptr && j < M) {
        for (int k = kg; k < K; k += 4) s += shift[k] * W[(long)k * M + j];
    }
    red[kg][jl] = s;
    __syncthreads();
    if (kg == 0 && j < Mp)
        wbias[j] = red[0][jl] + red[1][jl] + red[2][jl] + red[3][jl];
}

// ---------------- MFMA GEMM ----------------
// h2[i][j] = bf16( (Xb[i,:]·Wt[j,:] + wbias[j]) * dinv[i] ),  i<N, j<Mp (pad cols = 0)
template<int KP>
__global__ __launch_bounds__(64) void k_gemm_mfma(
    const ushort_t* __restrict__ Xb, const ushort_t* __restrict__ Wt,
    const float* __restrict__ wbias, const float* __restrict__ dinv,
    ushort_t* __restrict__ h2, int N, int Mp)
{
    typedef __attribute__((ext_vector_type(8))) short short8;
    typedef __attribute__((ext_vector_type(4))) float floatx4;
    const int lane = threadIdx.x;
    const int m = lane & 15;
    const int quad = lane >> 4;
    const int i0 = blockIdx.x * 16;
    const int j0 = blockIdx.y * 64;
    const int ntiles = min(4, (Mp - j0) >> 4);

    floatx4 acc[4];
    #pragma unroll
    for (int t = 0; t < 4; ++t) { acc[t].x = 0.f; acc[t].y = 0.f; acc[t].z = 0.f; acc[t].w = 0.f; }

    const int ra = min(i0 + m, N - 1);
    const ushort_t* arow = Xb + (long)ra * KP + quad * 8;
    const ushort_t* brow = Wt + (long)(j0 + m) * KP + quad * 8;

    #pragma unroll
    for (int k0 = 0; k0 < KP; k0 += 32) {
        short8 av = *(const short8*)(arow + k0);
        #pragma unroll
        for (int t = 0; t < 4; ++t) {
            if (t < ntiles) {
                short8 bv = *(const short8*)(brow + (long)t * 16 * KP + k0);
                acc[t] = __builtin_amdgcn_mfma_f32_16x16x32_bf16(av, bv, acc[t], 0, 0, 0);
            }
        }
    }

    #pragma unroll
    for (int t = 0; t < 4; ++t) {
        if (t < ntiles) {
            int j = j0 + t * 16 + m;
            float wb = wbias[j];
            #pragma unroll
            for (int r = 0; r < 4; ++r) {
                int i = i0 + quad * 4 + r;
                if (i < N) h2[(long)i * Mp + j] = f2bf((acc[t][r] + wb) * dinv[i]);
            }
        }
    }
}

// ---------------- aggregation (CSR gather, bf16 pairs) ----------------
// mode 0: tmpb[i][j] = bf16(relu(acc*dinv+b)), pad cols [M,2*halfK) zeroed
// mode 1: tmpf[i][j] = acc*dinv+b (fp32, j<M only)
__global__ __launch_bounds__(256) void k_agg(
    const int* __restrict__ row_start, const int* __restrict__ csr_src,
    const ushort_t* __restrict__ h2, int hstride,
    const float* __restrict__ dinv, const float* __restrict__ b,
    ushort_t* __restrict__ tmpb, int tstride, float* __restrict__ tmpf,
    int N, int M, int halfK, int mode)
{
    const int jp = threadIdx.x;
    const int i = blockIdx.x * 2 + threadIdx.y;
    if (i >= N || jp >= halfK) return;
    const int j0 = jp * 2;
    if (j0 >= M) {
        if (mode == 0) ((uint_t*)(tmpb + (long)i * tstride))[jp] = 0u;
        return;
    }
    const int s0 = row_start[i];
    const int s1 = row_start[i + 1];
    const ushort_t* hrow = h2 + (long)i * hstride;
    uint_t v = *(const uint_t*)(hrow + j0);
    float a0 = bf2f((ushort_t)(v & 0xffff));
    float a1 = bf2f((ushort_t)(v >> 16));
    int e = s0;
    for (; e + 3 < s1; e += 4) {
        int n0 = csr_src[e], n1 = csr_src[e + 1], n2 = csr_src[e + 2], n3 = csr_src[e + 3];
        uint_t w0 = *(const uint_t*)(h2 + (long)n0 * hstride + j0);
        uint_t w1 = *(const uint_t*)(h2 + (long)n1 * hstride + j0);
        uint_t w2 = *(const uint_t*)(h2 + (long)n2 * hstride + j0);
        uint_t w3 = *(const uint_t*)(h2 + (long)n3 * hstride + j0);
        a0 += bf2f((ushort_t)(w0 & 0xffff)); a1 += bf2f((ushort_t)(w0 >> 16));
        a0 += bf2f((ushort_t)(w1 & 0xffff)); a1 += bf2f((ushort_t)(w1 >> 16));
        a0 += bf2f((ushort_t)(w2 & 0xffff)); a1 += bf2f((ushort_t)(w2 >> 16));
        a0 += bf2f((ushort_t)(w3 & 0xffff)); a1 += bf2f((ushort_t)(w3 >> 16));
    }
    for (; e < s1; ++e) {
        uint_t w = *(const uint_t*)(h2 + (long)csr_src[e] * hstride + j0);
        a0 += bf2f((ushort_t)(w & 0xffff));
        a1 += bf2f((ushort_t)(w >> 16));
    }
    const float di = dinv[i];
    const int j1 = j0 + 1;
    float r0 = a0 * di + b[j0];
    float r1 = (j1 < M) ? (a1 * di + b[j1]) : 0.f;
    if (mode == 0) {
        r0 = fmaxf(r0, 0.f);
        r1 = fmaxf(r1, 0.f);
        uint_t pk = (uint_t)f2bf(r0) | ((uint_t)f2bf(r1) << 16);
        ((uint_t*)(tmpb + (long)i * tstride))[jp] = pk;
    } else {
        float* orow = tmpf + (long)i * 32;
        orow[j0] = r0;
        if (j1 < M) orow[j1] = r1;
    }
}

// ---------------- BN stats / finalize ----------------

__global__ __launch_bounds__(256) void k_stats(
    const ushort_t* __restrict__ tmpb, int tstride,
    float* __restrict__ cs, float* __restrict__ csq, int N, int M)
{
    const int j = threadIdx.x;
    if (j >= M) return;
    const int i0 = blockIdx.x * 64;
    float s = 0.f, s2 = 0.f;
    for (int r = 0; r < 64; ++r) {
        int i = i0 + r;
        if (i < N) {
            float v = bf2f(tmpb[(long)i * tstride + j]);
            s += v; s2 += v * v;
        }
    }
    atomicAdd(&cs[j], s);
    atomicAdd(&csq[j], s2);
}

__global__ void k_bn_finalize(
    const float* __restrict__ g, const float* __restrict__ be,
    float* __restrict__ cs, float* __restrict__ csq,
    float* __restrict__ scale, float* __restrict__ shift,
    int M, float invN)
{
    int j = threadIdx.x;
    if (j < M) {
        float mu  = cs[j] * invN;
        float var = csq[j] * invN - mu * mu;
        float sc  = g[j] * rsqrtf(var + 1e-5f);
        scale[j] = sc;
        shift[j] = be[j] - mu * sc;
    }
    if (j < 256) { cs[j] = 0.f; csq[j] = 0.f; }
}

// ---------------- final log_softmax ----------------

__global__ void k_final(const float* __restrict__ tmpf, float* __restrict__ out, int N) {
    int i = blockIdx.x * blockDim.x + threadIdx.x;
    if (i >= N) return;
    const int M = 17;
    float v[17];
    float m = -INFINITY;
    #pragma unroll
    for (int j = 0; j < M; ++j) { v[j] = tmpf[(long)i * 32 + j]; m = fmaxf(m, v[j]); }
    float s = 0.f;
    #pragma unroll
    for (int j = 0; j < M; ++j) s += expf(v[j] - m);
    float l = logf(s) + m;
    #pragma unroll
    for (int j = 0; j < M; ++j) out[(long)i * M + j] = v[j] - l;
}

// ---------------- launch ----------------

static inline int pad16(int v) { return (v + 15) & ~15; }
static inline int pad32(int v) { return (v + 31) & ~31; }

extern "C" void kernel_launch(void* const* d_in, const int* in_sizes, int n_in,
                              void* d_out, int out_size, void* d_ws, size_t ws_size,
                              hipStream_t stream)
{
    const int dims[6] = {256, 220, 150, 100, 60, 17};
    const int N = in_sizes[0] / dims[0];      // 10000
    const int E = in_sizes[1] / 2;            // 320000

    const float* x  = (const float*)d_in[0];
    const int* ei   = (const int*)d_in[1];
    const int* srcv = ei;
    const int* dstv = ei + E;
    const float* Wl[5], *bl[5];
    for (int l = 0; l < 5; ++l) {
        Wl[l] = (const float*)d_in[2 + 2 * l];
        bl[l] = (const float*)d_in[3 + 2 * l];
    }
    const float* gl[4], *bel[4];
    for (int l = 0; l < 4; ++l) {
        gl[l]  = (const float*)d_in[12 + 2 * l];
        bel[l] = (const float*)d_in[13 + 2 * l];
    }
    float* out = (float*)d_out;

    // ---- workspace layout (bytes, 256-aligned) ----
    char* w = (char*)d_ws;
    const long NB   = ((long)N * 4 + 255) & ~255L;
    const long NB1  = ((long)(N + 1) * 4 + 255) & ~255L;
    const long EB   = ((long)E * 4 + 255) & ~255L;
    const long XBB  = ((long)N * 256 * 2 + 255) & ~255L;   // bf16 x
    const long FBB  = ((long)N * 224 * 2 + 255) & ~255L;   // bf16 feature buf
    const long WTB  = ((long)224 * 256 * 2 + 255) & ~255L; // bf16 Wt (max)
    const long TFB  = ((long)N * 32 * 4 + 255) & ~255L;    // fp32 final logits

    long o = 0;
    float* dinv      = (float*)(w + o);  o += NB;
    float* cs        = (float*)(w + o);  o += 1024;
    float* csq       = (float*)(w + o);  o += 1024;
    float* scl       = (float*)(w + o);  o += 1024;
    float* shf       = (float*)(w + o);  o += 1024;
    float* wbias     = (float*)(w + o);  o += 1024;
    int*   cnt       = (int*)(w + o);    o += NB;
    int*   row_start = (int*)(w + o);    o += NB1;
    int*   cursor    = (int*)(w + o);    o += NB;
    int*   csr_src   = (int*)(w + o);    o += EB;
    ushort_t* xb     = (ushort_t*)(w + o); o += XBB;
    ushort_t* Wt     = (ushort_t*)(w + o); o += WTB;
    ushort_t* h2     = (ushort_t*)(w + o); o += FBB;
    ushort_t* tmpb   = (ushort_t*)(w + o); o += FBB;
    float* tmpf      = (float*)(w + o);    o += TFB;

    const int nBlk = (N + 255) / 256;
    const int eBlk = (E + 255) / 256;

    k_zero<<<nBlk, 256, 0, stream>>>(cnt, cs, csq, N);
    k_hist<<<eBlk, 256, 0, stream>>>(dstv, cnt, E);
    k_scan<<<1, 1024, 0, stream>>>(cnt, row_start, cursor, dinv, N);
    k_fill<<<eBlk, 256, 0, stream>>>(srcv, dstv, cursor, csr_src, E);
    k_cvtx<<<(N * 256 + 255) / 256, 256, 0, stream>>>(x, xb, N * 256);

    const float invN = 1.0f / (float)N;

    for (int l = 0; l < 5; ++l) {
        const int K  = dims[l];
        const int M  = dims[l + 1];
        const int Kp = pad32(K);                 // input stride (multiple of 32)
        const int Mp = pad16(M);                 // h2 stride
        const int KpN = (l < 4) ? pad32(M) : 32; // tmp stride for next layer / final
        const ushort_t* X = (l == 0) ? xb : tmpb;
        const float* sc_p = (l == 0) ? nullptr : scl;
        const float* sh_p = (l == 0) ? nullptr : shf;

        k_prepW<<<dim3((Kp + 63) / 64, Mp), 64, 0, stream>>>(Wl[l], sc_p, Wt, K, M, Kp);
        k_prepb<<<(Mp + 63) / 64, 256, 0, stream>>>(Wl[l], sh_p, wbias, K, M, Mp);

        dim3 gg((N + 15) / 16, (Mp + 63) / 64);
        switch (Kp) {
            case 256: k_gemm_mfma<256><<<gg, 64, 0, stream>>>(X, Wt, wbias, dinv, h2, N, Mp); break;
            case 224: k_gemm_mfma<224><<<gg, 64, 0, stream>>>(X, Wt, wbias, dinv, h2, N, Mp); break;
            case 160: k_gemm_mfma<160><<<gg, 64, 0, stream>>>(X, Wt, wbias, dinv, h2, N, Mp); break;
            case 128: k_gemm_mfma<128><<<gg, 64, 0, stream>>>(X, Wt, wbias, dinv, h2, N, Mp); break;
            case  64: k_gemm_mfma< 64><<<gg, 64, 0, stream>>>(X, Wt, wbias, dinv, h2, N, Mp); break;
        }

        const int halfK = KpN / 2;
        dim3 ablk(128, 2);
        k_agg<<<(N + 1) / 2, ablk, 0, stream>>>(row_start, csr_src, h2, Mp, dinv, bl[l],
                                                tmpb, KpN, tmpf, N, M, halfK,
                                                (l < 4) ? 0 : 1);

        if (l < 4) {
            k_stats<<<(N + 63) / 64, 256, 0, stream>>>(tmpb, KpN, cs, csq, N, M);
            k_bn_finalize<<<1, 256, 0, stream>>>(gl[l], bel[l], cs, csq, scl, shf, M, invN);
        } else {
            k_final<<<nBlk, 256, 0, stream>>>(tmpf, out, N);
        }
    }
}

// Round 6
// 431.690 us; speedup vs baseline: 2.9344x; 1.0019x over previous
//
#include <hip/hip_runtime.h>
#include <math.h>

typedef unsigned short ushort_t;
typedef unsigned int uint_t;
typedef unsigned long long ull_t;

__device__ __forceinline__ float bf2f(ushort_t u) {
    union { uint_t i; float f; } x; x.i = ((uint_t)u) << 16; return x.f;
}
__device__ __forceinline__ ushort_t f2bf(float f) {
    union { float f; uint_t i; } x; x.f = f;
    uint_t r = x.i + 0x7FFFu + ((x.i >> 16) & 1u);
    return (ushort_t)(r >> 16);
}

// ---------------- CSR construction ----------------

__global__ void k_zero(int* __restrict__ cnt, float* __restrict__ cs,
                       float* __restrict__ csq, int n) {
    int i = blockIdx.x * blockDim.x + threadIdx.x;
    if (i < n) cnt[i] = 0;
    if (i < 256) { cs[i] = 0.f; csq[i] = 0.f; }
}

__global__ void k_hist(const int* __restrict__ dst, int* __restrict__ cnt, int E) {
    int e = blockIdx.x * blockDim.x + threadIdx.x;
    if (e < E) atomicAdd(&cnt[dst[e]], 1);
}

__global__ __launch_bounds__(1024) void k_scan(
    const int* __restrict__ cnt, int* __restrict__ row_start,
    int* __restrict__ cursor, float* __restrict__ dinv, int N)
{
    __shared__ int sh[1024];
    const int tid = threadIdx.x;
    const int chunk = (N + 1023) >> 10;
    int loc[16];
    const int base = tid * chunk;
    int sum = 0;
    for (int c = 0; c < chunk; ++c) {
        int i = base + c;
        int v = (i < N) ? cnt[i] : 0;
        loc[c] = sum;
        sum += v;
    }
    sh[tid] = sum;
    __syncthreads();
    for (int off = 1; off < 1024; off <<= 1) {
        int v = (tid >= off) ? sh[tid - off] : 0;
        __syncthreads();
        sh[tid] += v;
        __syncthreads();
    }
    const int excl = sh[tid] - sum;
    for (int c = 0; c < chunk; ++c) {
        int i = base + c;
        if (i < N) {
            int rs = excl + loc[c];
            row_start[i] = rs;
            cursor[i] = rs;
            dinv[i] = rsqrtf(1.0f + (float)cnt[i]);
        }
    }
    if (tid == 1023) row_start[N] = sh[1023];
}

__global__ void k_fill(const int* __restrict__ src, const int* __restrict__ dst,
                       int* __restrict__ cursor, int* __restrict__ csr_src, int E) {
    int e = blockIdx.x * blockDim.x + threadIdx.x;
    if (e < E) {
        int pos = atomicAdd(&cursor[dst[e]], 1);
        csr_src[pos] = src[e];
    }
}

// ---------------- prep kernels ----------------

__global__ void k_cvtx(const float* __restrict__ x, ushort_t* __restrict__ xb, int n4) {
    int i = blockIdx.x * 256 + threadIdx.x;
    if (i < n4) {
        const float4 v = ((const float4*)x)[i];
        ushort_t* o = xb + i * 4;
        o[0] = f2bf(v.x); o[1] = f2bf(v.y); o[2] = f2bf(v.z); o[3] = f2bf(v.w);
    }
}

// Wt[j][k] = bf16(scale[k] * W[k][j]), zero-padded to Mp x Kp. block (64,4)
__global__ void k_prepW(const float* __restrict__ W, const float* __restrict__ scale,
                        ushort_t* __restrict__ Wt, int K, int M, int Kp, int Mp)
{
    int k = blockIdx.x * 64 + threadIdx.x;
    int j = blockIdx.y * 4 + threadIdx.y;
    if (k >= Kp || j >= Mp) return;
    float v = 0.f;
    if (k < K && j < M) {
        float s = (scale != nullptr) ? scale[k] : 1.f;
        v = s * W[(long)k * M + j];
    }
    Wt[(long)j * Kp + k] = f2bf(v);
}

// wbias[j] = sum_k shift[k]*W[k][j]; 64 j-lanes x 4 k-groups per block
__global__ __launch_bounds__(256) void k_prepb(
    const float* __restrict__ W, const float* __restrict__ shift,
    float* __restrict__ wbias, int K, int M, int Mp)
{
    __shared__ float red[4][64];
    const int jl = threadIdx.x & 63;
    const int kg = threadIdx.x >> 6;
    const int j = blockIdx.x * 64 + jl;
    float s = 0.f;
    if (shift != nullptr && j < M) {
        for (int k = kg; k < K; k += 4) s += shift[k] * W[(long)k * M + j];
    }
    red[kg][jl] = s;
    __syncthreads();
    if (kg == 0 && j < Mp)
        wbias[j] = red[0][jl] + red[1][jl] + red[2][jl] + red[3][jl];
}

// ---------------- MFMA GEMM ----------------
// h2[i][j] = bf16( (Xb[i,:]·Wt[j,:] + wbias[j]) * dinv[i] ),  i<N, j<Mp (pad cols -> 0)
template<int KP>
__global__ __launch_bounds__(64) void k_gemm_mfma(
    const ushort_t* __restrict__ Xb, const ushort_t* __restrict__ Wt,
    const float* __restrict__ wbias, const float* __restrict__ dinv,
    ushort_t* __restrict__ h2, int N, int Mp)
{
    typedef __attribute__((ext_vector_type(8))) short short8;
    typedef __attribute__((ext_vector_type(4))) float floatx4;
    const int lane = threadIdx.x;
    const int m = lane & 15;
    const int quad = lane >> 4;
    const int i0 = blockIdx.x * 16;
    const int j0 = blockIdx.y * 64;
    const int ntiles = min(4, (Mp - j0) >> 4);

    floatx4 acc[4];
    #pragma unroll
    for (int t = 0; t < 4; ++t) { acc[t].x = 0.f; acc[t].y = 0.f; acc[t].z = 0.f; acc[t].w = 0.f; }

    const int ra = min(i0 + m, N - 1);
    const ushort_t* arow = Xb + (long)ra * KP + quad * 8;
    const ushort_t* brow = Wt + (long)(j0 + m) * KP + quad * 8;

    #pragma unroll
    for (int k0 = 0; k0 < KP; k0 += 32) {
        short8 av = *(const short8*)(arow + k0);
        #pragma unroll
        for (int t = 0; t < 4; ++t) {
            if (t < ntiles) {
                short8 bv = *(const short8*)(brow + (long)t * 16 * KP + k0);
                acc[t] = __builtin_amdgcn_mfma_f32_16x16x32_bf16(av, bv, acc[t], 0, 0, 0);
            }
        }
    }

    #pragma unroll
    for (int t = 0; t < 4; ++t) {
        if (t < ntiles) {
            int j = j0 + t * 16 + m;
            float wb = wbias[j];
            #pragma unroll
            for (int r = 0; r < 4; ++r) {
                int i = i0 + quad * 4 + r;
                if (i < N) h2[(long)i * Mp + j] = f2bf((acc[t][r] + wb) * dinv[i]);
            }
        }
    }
}

// ---------------- aggregation (CSR gather, uint2 = 4 bf16/thread) ----------------
// tmpb[i][4jp..4jp+3] = bf16(relu(acc*dinv+b)); pad cols zeroed.
// Flat index: g = i*Q + jp, i = (g*magic)>>sh (64-bit magic division by Q).
__global__ __launch_bounds__(256) void k_agg(
    const int* __restrict__ row_start, const int* __restrict__ csr_src,
    const ushort_t* __restrict__ h2, int hs,
    const float* __restrict__ dinv, const float* __restrict__ b,
    ushort_t* __restrict__ tmpb, int ts,
    int N, int M, int Q, ull_t magic, uint_t sh)
{
    const uint_t g = blockIdx.x * 256 + threadIdx.x;
    const uint_t i = (uint_t)(((ull_t)g * magic) >> sh);
    const int jp = (int)(g - i * Q);
    if (i >= (uint_t)N) return;
    const int j0 = jp * 4;
    if (j0 >= M) {
        *(uint2*)(tmpb + (long)i * ts + j0) = make_uint2(0u, 0u);
        return;
    }
    const int s0 = row_start[i];
    const int s1 = row_start[i + 1];
    const ushort_t* hp = h2 + j0;
    uint2 v = *(const uint2*)(hp + (long)i * hs);
    float a0 = bf2f((ushort_t)(v.x & 0xffff)), a1 = bf2f((ushort_t)(v.x >> 16));
    float a2 = bf2f((ushort_t)(v.y & 0xffff)), a3 = bf2f((ushort_t)(v.y >> 16));
    int e = s0;
    for (; e + 3 < s1; e += 4) {
        int n0 = csr_src[e], n1 = csr_src[e + 1], n2 = csr_src[e + 2], n3 = csr_src[e + 3];
        uint2 w0 = *(const uint2*)(hp + (long)n0 * hs);
        uint2 w1 = *(const uint2*)(hp + (long)n1 * hs);
        uint2 w2 = *(const uint2*)(hp + (long)n2 * hs);
        uint2 w3 = *(const uint2*)(hp + (long)n3 * hs);
        a0 += bf2f((ushort_t)(w0.x & 0xffff)); a1 += bf2f((ushort_t)(w0.x >> 16));
        a2 += bf2f((ushort_t)(w0.y & 0xffff)); a3 += bf2f((ushort_t)(w0.y >> 16));
        a0 += bf2f((ushort_t)(w1.x & 0xffff)); a1 += bf2f((ushort_t)(w1.x >> 16));
        a2 += bf2f((ushort_t)(w1.y & 0xffff)); a3 += bf2f((ushort_t)(w1.y >> 16));
        a0 += bf2f((ushort_t)(w2.x & 0xffff)); a1 += bf2f((ushort_t)(w2.x >> 16));
        a2 += bf2f((ushort_t)(w2.y & 0xffff)); a3 += bf2f((ushort_t)(w2.y >> 16));
        a0 += bf2f((ushort_t)(w3.x & 0xffff)); a1 += bf2f((ushort_t)(w3.x >> 16));
        a2 += bf2f((ushort_t)(w3.y & 0xffff)); a3 += bf2f((ushort_t)(w3.y >> 16));
    }
    for (; e < s1; ++e) {
        uint2 w = *(const uint2*)(hp + (long)csr_src[e] * hs);
        a0 += bf2f((ushort_t)(w.x & 0xffff)); a1 += bf2f((ushort_t)(w.x >> 16));
        a2 += bf2f((ushort_t)(w.y & 0xffff)); a3 += bf2f((ushort_t)(w.y >> 16));
    }
    const float di = dinv[i];
    float r0 = (j0     < M) ? fmaxf(a0 * di + b[j0],     0.f) : 0.f;
    float r1 = (j0 + 1 < M) ? fmaxf(a1 * di + b[j0 + 1], 0.f) : 0.f;
    float r2 = (j0 + 2 < M) ? fmaxf(a2 * di + b[j0 + 2], 0.f) : 0.f;
    float r3 = (j0 + 3 < M) ? fmaxf(a3 * di + b[j0 + 3], 0.f) : 0.f;
    uint2 pk;
    pk.x = (uint_t)f2bf(r0) | ((uint_t)f2bf(r1) << 16);
    pk.y = (uint_t)f2bf(r2) | ((uint_t)f2bf(r3) << 16);
    *(uint2*)(tmpb + (long)i * ts + j0) = pk;
}

// ---------------- final layer: gather + bias + log_softmax fused ----------------
// h2 stride fixed 32; block (16,16): lane x covers cols 2x,2x+1; 16 rows/block.
__global__ __launch_bounds__(256) void k_agg_final(
    const int* __restrict__ row_start, const int* __restrict__ csr_src,
    const ushort_t* __restrict__ h2, const float* __restrict__ dinv,
    const float* __restrict__ b, float* __restrict__ out, int N, int M)
{
    const int x = threadIdx.x;                 // 0..15
    const int i = blockIdx.x * 16 + threadIdx.y;
    if (i >= N) return;
    const int j0 = 2 * x, j1 = 2 * x + 1;
    uint_t v = *(const uint_t*)(h2 + (long)i * 32 + j0);
    float a0 = bf2f((ushort_t)(v & 0xffff));
    float a1 = bf2f((ushort_t)(v >> 16));
    const int s0 = row_start[i];
    const int s1 = row_start[i + 1];
    int e = s0;
    for (; e + 1 < s1; e += 2) {
        int n0 = csr_src[e], n1 = csr_src[e + 1];
        uint_t w0 = *(const uint_t*)(h2 + (long)n0 * 32 + j0);
        uint_t w1 = *(const uint_t*)(h2 + (long)n1 * 32 + j0);
        a0 += bf2f((ushort_t)(w0 & 0xffff)); a1 += bf2f((ushort_t)(w0 >> 16));
        a0 += bf2f((ushort_t)(w1 & 0xffff)); a1 += bf2f((ushort_t)(w1 >> 16));
    }
    for (; e < s1; ++e) {
        uint_t w = *(const uint_t*)(h2 + (long)csr_src[e] * 32 + j0);
        a0 += bf2f((ushort_t)(w & 0xffff)); a1 += bf2f((ushort_t)(w >> 16));
    }
    const float di = dinv[i];
    float r0 = (j0 < M) ? (a0 * di + b[j0]) : -INFINITY;
    float r1 = (j1 < M) ? (a1 * di + b[j1]) : -INFINITY;
    float m = fmaxf(r0, r1);
    #pragma unroll
    for (int msk = 1; msk < 16; msk <<= 1) m = fmaxf(m, __shfl_xor(m, msk, 16));
    float s = ((j0 < M) ? expf(r0 - m) : 0.f) + ((j1 < M) ? expf(r1 - m) : 0.f);
    #pragma unroll
    for (int msk = 1; msk < 16; msk <<= 1) s += __shfl_xor(s, msk, 16);
    const float l = logf(s) + m;
    if (j0 < M) out[(long)i * M + j0] = r0 - l;
    if (j1 < M) out[(long)i * M + j1] = r1 - l;
}

// ---------------- BN stats / finalize ----------------
// uint loads: thread t covers cols 2t,2t+1 (pads are zero -> harmless in sums)
__global__ __launch_bounds__(256) void k_stats(
    const ushort_t* __restrict__ tmpb, int ts,
    float* __restrict__ cs, float* __restrict__ csq, int N)
{
    const int t = threadIdx.x;
    if (2 * t >= ts) return;
    const int i0 = blockIdx.x * 64;
    float s0 = 0.f, q0 = 0.f, s1 = 0.f, q1 = 0.f;
    for (int r = 0; r < 64; ++r) {
        int i = i0 + r;
        if (i < N) {
            uint_t w = *(const uint_t*)(tmpb + (long)i * ts + 2 * t);
            float v0 = bf2f((ushort_t)(w & 0xffff));
            float v1 = bf2f((ushort_t)(w >> 16));
            s0 += v0; q0 += v0 * v0;
            s1 += v1; q1 += v1 * v1;
        }
    }
    atomicAdd(&cs[2 * t], s0);
    atomicAdd(&csq[2 * t], q0);
    atomicAdd(&cs[2 * t + 1], s1);
    atomicAdd(&csq[2 * t + 1], q1);
}

__global__ void k_bn_finalize(
    const float* __restrict__ g, const float* __restrict__ be,
    float* __restrict__ cs, float* __restrict__ csq,
    float* __restrict__ scale, float* __restrict__ shift,
    int M, float invN)
{
    int j = threadIdx.x;
    if (j < M) {
        float mu  = cs[j] * invN;
        float var = csq[j] * invN - mu * mu;
        float sc  = g[j] * rsqrtf(var + 1e-5f);
        scale[j] = sc;
        shift[j] = be[j] - mu * sc;
    }
    if (j < 256) { cs[j] = 0.f; csq[j] = 0.f; }
}

// ---------------- launch ----------------

static inline int pad16(int v) { return (v + 15) & ~15; }
static inline int pad32(int v) { return (v + 31) & ~31; }

extern "C" void kernel_launch(void* const* d_in, const int* in_sizes, int n_in,
                              void* d_out, int out_size, void* d_ws, size_t ws_size,
                              hipStream_t stream)
{
    const int dims[6] = {256, 220, 150, 100, 60, 17};
    const int N = in_sizes[0] / dims[0];      // 10000
    const int E = in_sizes[1] / 2;            // 320000

    const float* x  = (const float*)d_in[0];
    const int* ei   = (const int*)d_in[1];
    const int* srcv = ei;
    const int* dstv = ei + E;
    const float* Wl[5], *bl[5];
    for (int l = 0; l < 5; ++l) {
        Wl[l] = (const float*)d_in[2 + 2 * l];
        bl[l] = (const float*)d_in[3 + 2 * l];
    }
    const float* gl[4], *bel[4];
    for (int l = 0; l < 4; ++l) {
        gl[l]  = (const float*)d_in[12 + 2 * l];
        bel[l] = (const float*)d_in[13 + 2 * l];
    }
    float* out = (float*)d_out;

    // ---- workspace layout (bytes, 256-aligned) ----
    char* w = (char*)d_ws;
    const long NB   = ((long)N * 4 + 255) & ~255L;
    const long NB1  = ((long)(N + 1) * 4 + 255) & ~255L;
    const long EB   = ((long)E * 4 + 255) & ~255L;
    const long XBB  = ((long)N * 256 * 2 + 255) & ~255L;   // bf16 x
    const long FBB  = ((long)N * 224 * 2 + 255) & ~255L;   // bf16 feature buf
    const long WTB  = ((long)224 * 256 * 2 + 255) & ~255L; // bf16 Wt (max)

    long o = 0;
    float* dinv      = (float*)(w + o);  o += NB;
    float* cs        = (float*)(w + o);  o += 1024;
    float* csq       = (float*)(w + o);  o += 1024;
    float* scl       = (float*)(w + o);  o += 1024;
    float* shf       = (float*)(w + o);  o += 1024;
    float* wbias     = (float*)(w + o);  o += 1024;
    int*   cnt       = (int*)(w + o);    o += NB;
    int*   row_start = (int*)(w + o);    o += NB1;
    int*   cursor    = (int*)(w + o);    o += NB;
    int*   csr_src   = (int*)(w + o);    o += EB;
    ushort_t* xb     = (ushort_t*)(w + o); o += XBB;
    ushort_t* Wt     = (ushort_t*)(w + o); o += WTB;
    ushort_t* h2     = (ushort_t*)(w + o); o += FBB;
    ushort_t* tmpb   = (ushort_t*)(w + o); o += FBB;

    const int nBlk = (N + 255) / 256;
    const int eBlk = (E + 255) / 256;

    k_zero<<<nBlk, 256, 0, stream>>>(cnt, cs, csq, N);
    k_hist<<<eBlk, 256, 0, stream>>>(dstv, cnt, E);
    k_scan<<<1, 1024, 0, stream>>>(cnt, row_start, cursor, dinv, N);
    k_fill<<<eBlk, 256, 0, stream>>>(srcv, dstv, cursor, csr_src, E);
    k_cvtx<<<(N * 64 + 255) / 256, 256, 0, stream>>>(x, xb, N * 64);

    const float invN = 1.0f / (float)N;

    for (int l = 0; l < 5; ++l) {
        const int K  = dims[l];
        const int M  = dims[l + 1];
        const int Kp = pad32(K);                 // input stride (multiple of 32)
        const int Mp = pad16(M);                 // h2 stride
        const int ts = (l < 4) ? pad32(M) : 32;  // tmp stride for next layer
        const ushort_t* X = (l == 0) ? xb : tmpb;
        const float* sc_p = (l == 0) ? nullptr : scl;
        const float* sh_p = (l == 0) ? nullptr : shf;

        k_prepW<<<dim3((Kp + 63) / 64, (Mp + 3) / 4), dim3(64, 4), 0, stream>>>(
            Wl[l], sc_p, Wt, K, M, Kp, Mp);
        k_prepb<<<(Mp + 63) / 64, 256, 0, stream>>>(Wl[l], sh_p, wbias, K, M, Mp);

        dim3 gg((N + 15) / 16, (Mp + 63) / 64);
        switch (Kp) {
            case 256: k_gemm_mfma<256><<<gg, 64, 0, stream>>>(X, Wt, wbias, dinv, h2, N, Mp); break;
            case 224: k_gemm_mfma<224><<<gg, 64, 0, stream>>>(X, Wt, wbias, dinv, h2, N, Mp); break;
            case 160: k_gemm_mfma<160><<<gg, 64, 0, stream>>>(X, Wt, wbias, dinv, h2, N, Mp); break;
            case 128: k_gemm_mfma<128><<<gg, 64, 0, stream>>>(X, Wt, wbias, dinv, h2, N, Mp); break;
            case  64: k_gemm_mfma< 64><<<gg, 64, 0, stream>>>(X, Wt, wbias, dinv, h2, N, Mp); break;
        }

        if (l < 4) {
            // 64-bit magic division by Q = ts/4 (uint32 magic overflows when Q is pow2!)
            const int Q = ts / 4;
            uint_t shmt = 0;
            while ((1u << shmt) < (uint_t)Q) ++shmt;
            shmt += 32;
            const ull_t magic = ((1ULL << shmt) + Q - 1) / (ull_t)Q;
            const long total = (long)N * Q;
            k_agg<<<(int)((total + 255) / 256), 256, 0, stream>>>(
                row_start, csr_src, h2, Mp, dinv, bl[l], tmpb, ts, N, M, Q, magic, shmt);

            k_stats<<<(N + 63) / 64, 256, 0, stream>>>(tmpb, ts, cs, csq, N);
            k_bn_finalize<<<1, 256, 0, stream>>>(gl[l], bel[l], cs, csq, scl, shf, M, invN);
        } else {
            k_agg_final<<<(N + 15) / 16, dim3(16, 16), 0, stream>>>(
                row_start, csr_src, h2, dinv, bl[l], out, N, M);
        }
    }
}